// Round 8
// baseline (140.068 us; speedup 1.0000x reference)
//
#include <hip/hip_runtime.h>
#include <cstddef>

#define N_TOT   8
#define R_TOT   2048
#define KK      16
#define CL      64
#define CM      128
#define EPSV    1e-5f
#define CNTF    262144.0f

typedef float    f32x4  __attribute__((ext_vector_type(4)));
typedef short    bf16x8 __attribute__((ext_vector_type(8)));
typedef unsigned u32x4  __attribute__((ext_vector_type(4)));

union FragU { bf16x8 f; unsigned u[4]; };

// Pre-packed weights (written by stats block 0) + final BN scale/shift
// (written by the LAST-finishing stats block via counter handshake).
__device__ float    g_w1f[72*4];      // float4 rows {w1_0,w1_1,w1_2,b1} per channel,
                                      // 8-row groups padded to stride 9 (bank spread)
__device__ unsigned g_w2p[8*64*4];    // packed bf16 B-frags for lift2
__device__ float    g_bn[8];          // {sc0,sc1,sc2,sh0,sh1,sh2,0,0}
__device__ unsigned g_cnt = 0;        // stats completion counter (self-resetting)

__device__ __forceinline__ float elu_f(float x){
    return x > 0.f ? x : (__expf(x) - 1.f);
}

#if defined(__has_builtin) && __has_builtin(__builtin_amdgcn_cvt_pk_bf16_f32)
__device__ __forceinline__ unsigned pk_bf16(float a, float b){
    auto v = __builtin_amdgcn_cvt_pk_bf16_f32(a, b);   // lo=a, hi=b
    unsigned u; __builtin_memcpy(&u, &v, 4);
    return u;
}
#else
__device__ __forceinline__ unsigned pk_bf16(float a, float b){
    unsigned ua = __float_as_uint(a), ub = __float_as_uint(b);
    ua += 0x7fff + ((ua >> 16) & 1);
    ub += 0x7fff + ((ub >> 16) & 1);
    return (ua >> 16) | (ub & 0xffff0000u);
}
#endif
__device__ __forceinline__ float bf_lo(unsigned u){ return __uint_as_float(u << 16); }
__device__ __forceinline__ float bf_hi(unsigned u){ return __uint_as_float(u & 0xffff0000u); }

__device__ __forceinline__ void split4(const float* x, unsigned* o){
    unsigned h01 = pk_bf16(x[0], x[1]);
    unsigned h23 = pk_bf16(x[2], x[3]);
    float l0 = x[0] - bf_lo(h01), l1 = x[1] - bf_hi(h01);
    float l2 = x[2] - bf_lo(h23), l3 = x[3] - bf_hi(h23);
    o[0] = h01; o[1] = h23; o[2] = pk_bf16(l0, l1); o[3] = pk_bf16(l2, l3);
}

// ---------------- Pass 1: BN partials + weight pre-pack + last-block BN finish ----
// R12: fold the former 1-block xconv_bn kernel (pure launch overhead) into the
// last-finishing stats block. This is R10's fold WITHOUT the F-regroup that was
// bundled with it (main is byte-identical to R11/R5). Handshake: write partials
// -> release fence -> counter; block seeing old==255 acquires, reduces, resets.
// No spin-waits anywhere -> no deadlock possible regardless of residency.
__global__ __launch_bounds__(256) void xconv_stats(
    const float* __restrict__ p, const float* __restrict__ P,
    const float* __restrict__ w1, const float* __restrict__ b1,
    const float* __restrict__ w2,
    const float* __restrict__ gamma, const float* __restrict__ beta,
    float* __restrict__ ws)
{
    const int tid = threadIdx.x;
    const int g = blockIdx.x*256 + tid;                // group of 4 neighbor rows
    const float4* P4 = (const float4*)(P + (size_t)g*12);
    float4 a = P4[0], b = P4[1], c = P4[2];
    const int nr = g >> 2;
    float pp0 = p[nr*3], pp1 = p[nr*3+1], pp2 = p[nr*3+2];
    float vx0=a.x-pp0, vx1=a.w-pp0, vx2=b.z-pp0, vx3=c.y-pp0;
    float vy0=a.y-pp1, vy1=b.x-pp1, vy2=b.w-pp1, vy3=c.z-pp1;
    float vz0=a.z-pp2, vz1=b.y-pp2, vz2=c.x-pp2, vz3=c.w-pp2;
    float s1[3], s2[3];
    s1[0]=vx0+vx1+vx2+vx3; s2[0]=vx0*vx0+vx1*vx1+vx2*vx2+vx3*vx3;
    s1[1]=vy0+vy1+vy2+vy3; s2[1]=vy0*vy0+vy1*vy1+vy2*vy2+vy3*vy3;
    s1[2]=vz0+vz1+vz2+vz3; s2[2]=vz0*vz0+vz1*vz1+vz2*vz2+vz3*vz3;

    #pragma unroll
    for (int off = 32; off > 0; off >>= 1){
        #pragma unroll
        for (int d = 0; d < 3; d++){
            s1[d] += __shfl_down(s1[d], off, 64);
            s2[d] += __shfl_down(s2[d], off, 64);
        }
    }
    __shared__ float red[4][6];
    __shared__ int   sLast;
    int wave = tid >> 6, lane = tid & 63;
    if (lane == 0){
        #pragma unroll
        for (int d = 0; d < 3; d++){ red[wave][d] = s1[d]; red[wave][3+d] = s2[d]; }
    }
    __syncthreads();
    if (tid < 8){
        float v = 0.f;
        if (tid < 6) v = red[0][tid] + red[1][tid] + red[2][tid] + red[3][tid];
        ws[blockIdx.x*8 + tid] = v;            // slots 6,7 = 0 (defined)
        __threadfence();                        // release partials (device scope)
    }

    // ---- weight pre-pack (block 0 only) ----
    if (blockIdx.x == 0){
        if (wave == 0){
            f32x4 w4 = { w1[lane], w1[64+lane], w1[128+lane], b1[lane] };
            *(f32x4*)&g_w1f[((lane>>3)*9 + (lane&7))*4] = w4;
        } else if (wave == 1){
            const int lo16 = lane & 15, quad = lane >> 4;
            #pragma unroll
            for (int bb = 0; bb < 4; bb++)
                #pragma unroll
                for (int s = 0; s < 2; s++){
                    u32x4 f;
                    #pragma unroll
                    for (int d = 0; d < 4; d++){
                        int q0 = s*32 + quad*8 + d*2;
                        int idx = q0*64 + bb*16 + lo16;
                        f[d] = pk_bf16(w2[idx], w2[idx + 64]);
                    }
                    *(u32x4*)&g_w2p[((bb*2 + s)*64 + lane)*4] = f;
                }
        }
    }

    // ---- last-block BN finish ----
    __syncthreads();
    if (tid == 0){
        unsigned old = atomicAdd(&g_cnt, 1u);
        sLast = (old == 255u);
        if (sLast) atomicExch(&g_cnt, 0u);     // reset for next launch/replay
    }
    __syncthreads();
    if (sLast && tid < 64){
        __threadfence();                        // acquire all blocks' partials
        float t1[3] = {0.f,0.f,0.f}, t2[3] = {0.f,0.f,0.f};
        const f32x4* wp = (const f32x4*)ws;
        #pragma unroll
        for (int i = 0; i < 4; i++){
            int row = tid + i*64;
            f32x4 pa = wp[row*2], pb = wp[row*2 + 1];
            t1[0] += pa.x; t1[1] += pa.y; t1[2] += pa.z;
            t2[0] += pa.w; t2[1] += pb.x; t2[2] += pb.y;
        }
        #pragma unroll
        for (int off = 32; off > 0; off >>= 1){
            #pragma unroll
            for (int d = 0; d < 3; d++){
                t1[d] += __shfl_xor(t1[d], off, 64);
                t2[d] += __shfl_xor(t2[d], off, 64);
            }
        }
        if (tid == 0){
            #pragma unroll
            for (int d = 0; d < 3; d++){
                float mean = t1[d] * (1.0f/CNTF);
                float var  = t2[d] * (1.0f/CNTF) - mean*mean;
                float s    = gamma[d] * rsqrtf(var + EPSV);
                g_bn[d] = s; g_bn[3+d] = beta[d] - mean*s;
            }
            g_bn[6] = 0.f; g_bn[7] = 0.f;
        }
    }
}

// ---------------- Pass 2: fused MFMA kernel ----------------
// BYTE-IDENTICAL to R11/R5 (139.5/138.8 best config): 4096 blocks x 256 thr,
// one point per wave, __launch_bounds__(256,6). Occupancy ladder measured:
// 4 waves=41us (R8), 5 waves=~30us (R9), 6 waves ~neutral (R11) -> TLP saturated;
// further gains must come from VALU cuts or fewer dispatches (this round).
__global__ __launch_bounds__(256, 6) void xconv_main(
    const float* __restrict__ p,   const float* __restrict__ P,
    const float* __restrict__ F,
    const float* __restrict__ mlpw,const float* __restrict__ mlpb,
    const float* __restrict__ midw,const float* __restrict__ midb,
    const float* __restrict__ b2,
    const float* __restrict__ endw,const float* __restrict__ endb,
    float* __restrict__ out)
{
    __shared__ float    sEndw[128*20];     // 10240 B, rows padded to 80 B
    __shared__ float    sW1f[72*4];        //  1152 B, {w1_0,w1_1,w1_2,b1} per channel
    __shared__ unsigned sW2[8*64*4];       //  8192 B, per-(b,s,lane) 16 B frags
    __shared__ float    sMid[16*4];        //   256 B, {mw0,mw1,mw2,mb} per out col

    const int tid  = threadIdx.x;
    const int lane = tid & 63;
    const int lo16 = lane & 15;
    const int quad = lane >> 4;
    const int wave = tid >> 6;

    // ---- parallel LDS staging (vector copies of pre-packed weights) ----
    if (wave == 0){
        *(f32x4*)&sW1f[lane*4] = *(const f32x4*)&g_w1f[lane*4];
        if (lane < 8)
            *(f32x4*)&sW1f[(64+lane)*4] = *(const f32x4*)&g_w1f[(64+lane)*4];
    } else if (wave == 1){
        #pragma unroll
        for (int i = 0; i < 8; i++)
            *(u32x4*)&sW2[(i*64+lane)*4] = *(const u32x4*)&g_w2p[(i*64+lane)*4];
    } else {
        int c = tid - 128;                 // 0..127
        const f32x4* ep = (const f32x4*)endw;
        #pragma unroll
        for (int i = 0; i < 4; i++)
            *(f32x4*)&sEndw[c*20 + i*4] = ep[c*4 + i];
        if (c >= 112){                     // last 16 threads also stage sMid
            int m2 = c - 112;
            f32x4 mv = { midw[m2], midw[16+m2], midw[32+m2], midb[m2] };
            *(f32x4*)&sMid[m2*4] = mv;
        }
    }

    // ---- BN scale/shift: precomputed by stats' last block, 8-float load ----
    f32x4 bn0 = *(const f32x4*)&g_bn[0];
    float sc0 = bn0.x, sc1 = bn0.y, sc2 = bn0.z, sh0 = bn0.w;
    float sh1 = g_bn[4], sh2 = g_bn[5];

    // ---- small persistent regs ----
    FragU mlpA[2];
    {
        float mw[4];
        #pragma unroll
        for (int r = 0; r < 4; r++) mw[r] = mlpw[(quad*4 + r)*16 + lo16];
        unsigned o[4]; split4(mw, o);
        mlpA[0].u[0]=o[0]; mlpA[0].u[1]=o[1]; mlpA[0].u[2]=o[0]; mlpA[0].u[3]=o[1];
        mlpA[1].u[0]=o[2]; mlpA[1].u[1]=o[3]; mlpA[1].u[2]=o[2]; mlpA[1].u[3]=o[3];
    }
    float mlpbr[4];
    #pragma unroll
    for (int r = 0; r < 4; r++) mlpbr[r] = mlpb[quad*4 + r];
    float b2r[4];
    #pragma unroll
    for (int b = 0; b < 4; b++) b2r[b] = b2[b*16 + lo16];
    const float endb0 = endb[lane], endb1 = endb[64 + lane];

    __syncthreads();

    const int nr = blockIdx.x*4 + wave;    // 0..16383, one point per wave

    // ---- P/p first (needed immediately), then F (needed last, max overlap) ----
    const int pb = nr*48 + lo16*3;
    float P0 = P[pb], P1 = P[pb+1], P2 = P[pb+2];
    float pp0 = p[nr*3], pp1 = p[nr*3+1], pp2 = p[nr*3+2];

    unsigned fh01[4], fh23[4];             // F packed to bf16 right at load
    #pragma unroll
    for (int bt = 0; bt < 4; bt++){
        const size_t fb = (size_t)nr*1024 + (size_t)(quad*4)*64 + bt*16 + lo16;
        float f0 = F[fb], f1 = F[fb + 64], f2 = F[fb + 128], f3 = F[fb + 192];
        fh01[bt] = pk_bf16(f0, f1);
        fh23[bt] = pk_bf16(f2, f3);
    }

    const float pn0 = (P0 - pp0)*sc0 + sh0;
    const float pn1 = (P1 - pp1)*sc1 + sh1;
    const float pn2 = (P2 - pp2)*sc2 + sh2;

    // ---- h1 = elu(Pn @ w1 + b1): fp32 weights, broadcast LDS reads ----
    FragU hf[2];
    #pragma unroll
    for (int s = 0; s < 2; s++){
        const f32x4* wp = (const f32x4*)&sW1f[((s*4 + quad)*9)*4];
        #pragma unroll
        for (int d = 0; d < 4; d++){
            f32x4 wa = wp[2*d], wb = wp[2*d+1];
            float h0  = fmaf(pn2, wa.z, fmaf(pn1, wa.y, fmaf(pn0, wa.x, wa.w)));
            float h1v = fmaf(pn2, wb.z, fmaf(pn1, wb.y, fmaf(pn0, wb.x, wb.w)));
            hf[s].u[d] = pk_bf16(elu_f(h0), elu_f(h1v));
        }
    }

    // ---- X0 (exact fp32) -> split B-frag ----
    float x0[4];
    #pragma unroll
    for (int j = 0; j < 4; j++){
        f32x4 mw = *(const f32x4*)&sMid[(quad*4 + j)*4];
        x0[j] = fmaf(pn2, mw.z, fmaf(pn1, mw.y, fmaf(pn0, mw.x, mw.w)));
    }
    FragU x0f; split4(x0, x0f.u);

    // ---- mlp: X^T = mlpw^T @ X0^T (exact), ELU, split -> agg A-frag ----
    f32x4 dx = {0.f,0.f,0.f,0.f};
    dx = __builtin_amdgcn_mfma_f32_16x16x32_bf16(mlpA[0].f, x0f.f, dx, 0,0,0);
    dx = __builtin_amdgcn_mfma_f32_16x16x32_bf16(mlpA[1].f, x0f.f, dx, 0,0,0);
    float xv[4];
    #pragma unroll
    for (int r = 0; r < 4; r++) xv[r] = elu_f(dx[r] + mlpbr[r]);
    FragU xA; split4(xv, xA.u);

    float o0 = 0.f, o1 = 0.f;

    // ---- tiles 0..3: lift2 (MFMA) -> ELU -> hi-dup B-frag -> agg ----
    #pragma unroll
    for (int b = 0; b < 4; b++){
        FragU wf0, wf1;
        *(u32x4*)wf0.u = *(const u32x4*)&sW2[((b*2 + 0)*64 + lane)*4];
        *(u32x4*)wf1.u = *(const u32x4*)&sW2[((b*2 + 1)*64 + lane)*4];
        f32x4 dl = {0.f,0.f,0.f,0.f};
        dl = __builtin_amdgcn_mfma_f32_16x16x32_bf16(hf[0].f, wf0.f, dl, 0,0,0);
        dl = __builtin_amdgcn_mfma_f32_16x16x32_bf16(hf[1].f, wf1.f, dl, 0,0,0);
        float fl[4];
        #pragma unroll
        for (int r = 0; r < 4; r++) fl[r] = elu_f(dl[r] + b2r[b]);
        FragU bfg;
        unsigned h01 = pk_bf16(fl[0], fl[1]), h23 = pk_bf16(fl[2], fl[3]);
        bfg.u[0] = h01; bfg.u[1] = h23; bfg.u[2] = h01; bfg.u[3] = h23;
        f32x4 da = {0.f,0.f,0.f,0.f};
        da = __builtin_amdgcn_mfma_f32_16x16x32_bf16(xA.f, bfg.f, da, 0,0,0);
        const float4 ew = *(const float4*)&sEndw[(b*16 + lo16)*20 + quad*4];
        float pt = da[0]*ew.x + da[1]*ew.y + da[2]*ew.z + da[3]*ew.w;
        pt += __shfl_xor(pt, 16, 64);
        pt += __shfl_xor(pt, 32, 64);
        if (b == quad) o0 = pt;            // c = b*16+lo16 == lane
    }
    // ---- tiles 4..7: raw F (pre-packed) -> hi-dup B-frag -> agg ----
    #pragma unroll
    for (int bt = 0; bt < 4; bt++){
        FragU bfg;
        bfg.u[0] = fh01[bt]; bfg.u[1] = fh23[bt];
        bfg.u[2] = fh01[bt]; bfg.u[3] = fh23[bt];
        f32x4 da = {0.f,0.f,0.f,0.f};
        da = __builtin_amdgcn_mfma_f32_16x16x32_bf16(xA.f, bfg.f, da, 0,0,0);
        const float4 ew = *(const float4*)&sEndw[(64 + bt*16 + lo16)*20 + quad*4];
        float pt = da[0]*ew.x + da[1]*ew.y + da[2]*ew.z + da[3]*ew.w;
        pt += __shfl_xor(pt, 16, 64);
        pt += __shfl_xor(pt, 32, 64);
        if (bt == quad) o1 = pt;           // c = 64 + bt*16+lo16 == 64+lane
    }

    out[(size_t)nr*CM + lane]      = o0 + endb0;
    out[(size_t)nr*CM + 64 + lane] = o1 + endb1;
}

extern "C" void kernel_launch(void* const* d_in, const int* in_sizes, int n_in,
                              void* d_out, int out_size, void* d_ws, size_t ws_size,
                              hipStream_t stream)
{
    const float* p     = (const float*)d_in[0];
    const float* P     = (const float*)d_in[1];
    const float* F     = (const float*)d_in[2];
    const float* gamma = (const float*)d_in[3];
    const float* beta  = (const float*)d_in[4];
    const float* w1    = (const float*)d_in[5];
    const float* b1    = (const float*)d_in[6];
    const float* w2    = (const float*)d_in[7];
    const float* b2    = (const float*)d_in[8];
    const float* midw  = (const float*)d_in[9];
    const float* midb  = (const float*)d_in[10];
    const float* mlpw  = (const float*)d_in[11];
    const float* mlpb  = (const float*)d_in[12];
    const float* endw  = (const float*)d_in[13];
    const float* endb  = (const float*)d_in[14];
    float* ws  = (float*)d_ws;
    float* out = (float*)d_out;

    xconv_stats<<<256, 256, 0, stream>>>(p, P, w1, b1, w2, gamma, beta, ws);
    xconv_main <<<4096, 256, 0, stream>>>(p, P, F, mlpw, mlpb, midw, midb,
                                          b2, endw, endb, out);
}

// Round 9
// 138.994 us; speedup vs baseline: 1.0077x; 1.0077x over previous
//
#include <hip/hip_runtime.h>
#include <cstddef>

#define N_TOT   8
#define R_TOT   2048
#define KK      16
#define CL      64
#define CM      128
#define EPSV    1e-5f
#define CNTF    262144.0f

typedef float    f32x4  __attribute__((ext_vector_type(4)));
typedef short    bf16x8 __attribute__((ext_vector_type(8)));
typedef unsigned u32x4  __attribute__((ext_vector_type(4)));

union FragU { bf16x8 f; unsigned u[4]; };

// Pre-packed weights (written by stats block 0) + final BN scale/shift
// (written by xconv_bn). Device globals: deterministic, rewritten each launch.
__device__ float    g_w1f[72*4];      // float4 rows {w1_0,w1_1,w1_2,b1} per channel,
                                      // 8-row groups padded to stride 9 (bank spread)
__device__ unsigned g_w2p[8*64*4];    // packed bf16 B-frags for lift2
__device__ float    g_bn[8];          // {sc0,sc1,sc2,sh0,sh1,sh2,0,0}

__device__ __forceinline__ float elu_f(float x){
    return x > 0.f ? x : (__expf(x) - 1.f);
}

#if defined(__has_builtin) && __has_builtin(__builtin_amdgcn_cvt_pk_bf16_f32)
__device__ __forceinline__ unsigned pk_bf16(float a, float b){
    auto v = __builtin_amdgcn_cvt_pk_bf16_f32(a, b);   // lo=a, hi=b
    unsigned u; __builtin_memcpy(&u, &v, 4);
    return u;
}
#else
__device__ __forceinline__ unsigned pk_bf16(float a, float b){
    unsigned ua = __float_as_uint(a), ub = __float_as_uint(b);
    ua += 0x7fff + ((ua >> 16) & 1);
    ub += 0x7fff + ((ub >> 16) & 1);
    return (ua >> 16) | (ub & 0xffff0000u);
}
#endif
__device__ __forceinline__ float bf_lo(unsigned u){ return __uint_as_float(u << 16); }
__device__ __forceinline__ float bf_hi(unsigned u){ return __uint_as_float(u & 0xffff0000u); }

__device__ __forceinline__ void split4(const float* x, unsigned* o){
    unsigned h01 = pk_bf16(x[0], x[1]);
    unsigned h23 = pk_bf16(x[2], x[3]);
    float l0 = x[0] - bf_lo(h01), l1 = x[1] - bf_hi(h01);
    float l2 = x[2] - bf_lo(h23), l3 = x[3] - bf_hi(h23);
    o[0] = h01; o[1] = h23; o[2] = pk_bf16(l0, l1); o[3] = pk_bf16(l2, l3);
}

// ---------------- Pass 1: per-block BN partials + weight pre-pack ----------------
// (R5-exact: best measured config 138.8us. R8 proved the bn-fold is neutral —
// dispatches are back-to-back under graph capture — so keep the simple form.)
__global__ __launch_bounds__(256) void xconv_stats(
    const float* __restrict__ p, const float* __restrict__ P,
    const float* __restrict__ w1, const float* __restrict__ b1,
    const float* __restrict__ w2, float* __restrict__ ws)
{
    const int tid = threadIdx.x;
    const int g = blockIdx.x*256 + tid;                // group of 4 neighbor rows
    const float4* P4 = (const float4*)(P + (size_t)g*12);
    float4 a = P4[0], b = P4[1], c = P4[2];
    const int nr = g >> 2;
    float pp0 = p[nr*3], pp1 = p[nr*3+1], pp2 = p[nr*3+2];
    float vx0=a.x-pp0, vx1=a.w-pp0, vx2=b.z-pp0, vx3=c.y-pp0;
    float vy0=a.y-pp1, vy1=b.x-pp1, vy2=b.w-pp1, vy3=c.z-pp1;
    float vz0=a.z-pp2, vz1=b.y-pp2, vz2=c.x-pp2, vz3=c.w-pp2;
    float s1[3], s2[3];
    s1[0]=vx0+vx1+vx2+vx3; s2[0]=vx0*vx0+vx1*vx1+vx2*vx2+vx3*vx3;
    s1[1]=vy0+vy1+vy2+vy3; s2[1]=vy0*vy0+vy1*vy1+vy2*vy2+vy3*vy3;
    s1[2]=vz0+vz1+vz2+vz3; s2[2]=vz0*vz0+vz1*vz1+vz2*vz2+vz3*vz3;

    #pragma unroll
    for (int off = 32; off > 0; off >>= 1){
        #pragma unroll
        for (int d = 0; d < 3; d++){
            s1[d] += __shfl_down(s1[d], off, 64);
            s2[d] += __shfl_down(s2[d], off, 64);
        }
    }
    __shared__ float red[4][6];
    int wave = tid >> 6, lane = tid & 63;
    if (lane == 0){
        #pragma unroll
        for (int d = 0; d < 3; d++){ red[wave][d] = s1[d]; red[wave][3+d] = s2[d]; }
    }
    __syncthreads();
    float v = 0.f;
    if (tid < 6) v = red[0][tid] + red[1][tid] + red[2][tid] + red[3][tid];
    if (tid < 8) ws[blockIdx.x*8 + tid] = v;           // slots 6,7 = 0 (defined)

    // ---- weight pre-pack (block 0 only) ----
    if (blockIdx.x == 0){
        if (wave == 0){
            f32x4 w4 = { w1[lane], w1[64+lane], w1[128+lane], b1[lane] };
            *(f32x4*)&g_w1f[((lane>>3)*9 + (lane&7))*4] = w4;
        } else if (wave == 1){
            const int lo16 = lane & 15, quad = lane >> 4;
            #pragma unroll
            for (int bb = 0; bb < 4; bb++)
                #pragma unroll
                for (int s = 0; s < 2; s++){
                    u32x4 f;
                    #pragma unroll
                    for (int d = 0; d < 4; d++){
                        int q0 = s*32 + quad*8 + d*2;
                        int idx = q0*64 + bb*16 + lo16;
                        f[d] = pk_bf16(w2[idx], w2[idx + 64]);
                    }
                    *(u32x4*)&g_w2p[((bb*2 + s)*64 + lane)*4] = f;
                }
        }
    }
}

// ---------------- Pass 1b: reduce BN partials -> sc/sh (1 block, 64 thr) ----------------
__global__ __launch_bounds__(64) void xconv_bn(
    const float* __restrict__ ws,
    const float* __restrict__ gamma, const float* __restrict__ beta)
{
    const int lane = threadIdx.x;
    float s1[3] = {0.f,0.f,0.f}, s2[3] = {0.f,0.f,0.f};
    const f32x4* wp = (const f32x4*)ws;
    #pragma unroll
    for (int i = 0; i < 4; i++){
        int row = lane + i*64;
        f32x4 pa = wp[row*2], pb = wp[row*2 + 1];
        s1[0] += pa.x; s1[1] += pa.y; s1[2] += pa.z;
        s2[0] += pa.w; s2[1] += pb.x; s2[2] += pb.y;
    }
    #pragma unroll
    for (int off = 32; off > 0; off >>= 1){
        #pragma unroll
        for (int d = 0; d < 3; d++){
            s1[d] += __shfl_xor(s1[d], off, 64);
            s2[d] += __shfl_xor(s2[d], off, 64);
        }
    }
    if (lane == 0){
        #pragma unroll
        for (int d = 0; d < 3; d++){
            float mean = s1[d] * (1.0f/CNTF);
            float var  = s2[d] * (1.0f/CNTF) - mean*mean;
            float s    = gamma[d] * rsqrtf(var + EPSV);
            g_bn[d] = s; g_bn[3+d] = beta[d] - mean*s;
        }
        g_bn[6] = 0.f; g_bn[7] = 0.f;
    }
}

// ---------------- Pass 2: fused MFMA kernel ----------------
// R13: 2048 blocks x 256 thr, TWO points per wave with explicitly interleaved
// chains. Regime: latency-bound (no pipe >45%, 5->6 waves flat), TLP capped by
// VGPR. 4 waves x 2 live chains = 8 chains/SIMD vs 6 (R11), and the per-tile
// LDS reads (wf0/wf1/ew), h1 weight reads, and block prologue amortize 2x.
// Per-point numerics bit-identical (chained MFMAs kept per point).
__global__ __launch_bounds__(256, 4) void xconv_main(
    const float* __restrict__ p,   const float* __restrict__ P,
    const float* __restrict__ F,
    const float* __restrict__ mlpw,const float* __restrict__ mlpb,
    const float* __restrict__ midw,const float* __restrict__ midb,
    const float* __restrict__ b2,
    const float* __restrict__ endw,const float* __restrict__ endb,
    float* __restrict__ out)
{
    __shared__ float    sEndw[128*20];     // 10240 B, rows padded to 80 B
    __shared__ float    sW1f[72*4];        //  1152 B, {w1_0,w1_1,w1_2,b1} per channel
    __shared__ unsigned sW2[8*64*4];       //  8192 B, per-(b,s,lane) 16 B frags
    __shared__ float    sMid[16*4];        //   256 B, {mw0,mw1,mw2,mb} per out col

    const int tid  = threadIdx.x;
    const int lane = tid & 63;
    const int lo16 = lane & 15;
    const int quad = lane >> 4;
    const int wave = tid >> 6;

    // ---- parallel LDS staging (vector copies of pre-packed weights) ----
    if (wave == 0){
        *(f32x4*)&sW1f[lane*4] = *(const f32x4*)&g_w1f[lane*4];
        if (lane < 8)
            *(f32x4*)&sW1f[(64+lane)*4] = *(const f32x4*)&g_w1f[(64+lane)*4];
    } else if (wave == 1){
        #pragma unroll
        for (int i = 0; i < 8; i++)
            *(u32x4*)&sW2[(i*64+lane)*4] = *(const u32x4*)&g_w2p[(i*64+lane)*4];
    } else {
        int c = tid - 128;                 // 0..127
        const f32x4* ep = (const f32x4*)endw;
        #pragma unroll
        for (int i = 0; i < 4; i++)
            *(f32x4*)&sEndw[c*20 + i*4] = ep[c*4 + i];
        if (c >= 112){                     // last 16 threads also stage sMid
            int m2 = c - 112;
            f32x4 mv = { midw[m2], midw[16+m2], midw[32+m2], midb[m2] };
            *(f32x4*)&sMid[m2*4] = mv;
        }
    }

    // ---- BN scale/shift: precomputed by xconv_bn, 8-float load ----
    f32x4 bn0 = *(const f32x4*)&g_bn[0];
    float sc0 = bn0.x, sc1 = bn0.y, sc2 = bn0.z, sh0 = bn0.w;
    float sh1 = g_bn[4], sh2 = g_bn[5];

    // ---- small persistent regs ----
    FragU mlpA[2];
    {
        float mw[4];
        #pragma unroll
        for (int r = 0; r < 4; r++) mw[r] = mlpw[(quad*4 + r)*16 + lo16];
        unsigned o[4]; split4(mw, o);
        mlpA[0].u[0]=o[0]; mlpA[0].u[1]=o[1]; mlpA[0].u[2]=o[0]; mlpA[0].u[3]=o[1];
        mlpA[1].u[0]=o[2]; mlpA[1].u[1]=o[3]; mlpA[1].u[2]=o[2]; mlpA[1].u[3]=o[3];
    }
    float mlpbr[4];
    #pragma unroll
    for (int r = 0; r < 4; r++) mlpbr[r] = mlpb[quad*4 + r];
    float b2r[4];
    #pragma unroll
    for (int b = 0; b < 4; b++) b2r[b] = b2[b*16 + lo16];
    const float endb0 = endb[lane], endb1 = endb[64 + lane];

    __syncthreads();

    const int nrA = (blockIdx.x*4 + wave)*2;   // 0..16382, two points per wave
    const int nrB = nrA + 1;

    // ---- loads for BOTH points up front (32 F + 6 P + 6 p issues, max MLP) ----
    const int pbA = nrA*48 + lo16*3;
    float PA0 = P[pbA],    PA1 = P[pbA+1],  PA2 = P[pbA+2];
    float PB0 = P[pbA+48], PB1 = P[pbA+49], PB2 = P[pbA+50];
    float ppA0 = p[nrA*3],   ppA1 = p[nrA*3+1], ppA2 = p[nrA*3+2];
    float ppB0 = p[nrA*3+3], ppB1 = p[nrA*3+4], ppB2 = p[nrA*3+5];

    unsigned fA01[4], fA23[4], fB01[4], fB23[4];
    #pragma unroll
    for (int bt = 0; bt < 4; bt++){
        const size_t fbA = (size_t)nrA*1024 + (size_t)(quad*4)*64 + bt*16 + lo16;
        float a0 = F[fbA], a1 = F[fbA+64], a2 = F[fbA+128], a3 = F[fbA+192];
        const size_t fbB = fbA + 1024;
        float c0 = F[fbB], c1 = F[fbB+64], c2 = F[fbB+128], c3 = F[fbB+192];
        fA01[bt] = pk_bf16(a0, a1); fA23[bt] = pk_bf16(a2, a3);
        fB01[bt] = pk_bf16(c0, c1); fB23[bt] = pk_bf16(c2, c3);
    }

    const float pnA0 = (PA0 - ppA0)*sc0 + sh0;
    const float pnA1 = (PA1 - ppA1)*sc1 + sh1;
    const float pnA2 = (PA2 - ppA2)*sc2 + sh2;
    const float pnB0 = (PB0 - ppB0)*sc0 + sh0;
    const float pnB1 = (PB1 - ppB1)*sc1 + sh1;
    const float pnB2 = (PB2 - ppB2)*sc2 + sh2;

    // ---- h1 = elu(Pn @ w1 + b1): shared LDS weight reads, both points ----
    FragU hfA[2], hfB[2];
    #pragma unroll
    for (int s = 0; s < 2; s++){
        const f32x4* wp = (const f32x4*)&sW1f[((s*4 + quad)*9)*4];
        #pragma unroll
        for (int d = 0; d < 4; d++){
            f32x4 wa = wp[2*d], wb = wp[2*d+1];
            float hA0 = fmaf(pnA2, wa.z, fmaf(pnA1, wa.y, fmaf(pnA0, wa.x, wa.w)));
            float hA1 = fmaf(pnA2, wb.z, fmaf(pnA1, wb.y, fmaf(pnA0, wb.x, wb.w)));
            hfA[s].u[d] = pk_bf16(elu_f(hA0), elu_f(hA1));
            float hB0 = fmaf(pnB2, wa.z, fmaf(pnB1, wa.y, fmaf(pnB0, wa.x, wa.w)));
            float hB1 = fmaf(pnB2, wb.z, fmaf(pnB1, wb.y, fmaf(pnB0, wb.x, wb.w)));
            hfB[s].u[d] = pk_bf16(elu_f(hB0), elu_f(hB1));
        }
    }

    // ---- X0 (exact fp32) -> split B-frags, both points ----
    float x0A[4], x0B[4];
    #pragma unroll
    for (int j = 0; j < 4; j++){
        f32x4 mw = *(const f32x4*)&sMid[(quad*4 + j)*4];
        x0A[j] = fmaf(pnA2, mw.z, fmaf(pnA1, mw.y, fmaf(pnA0, mw.x, mw.w)));
        x0B[j] = fmaf(pnB2, mw.z, fmaf(pnB1, mw.y, fmaf(pnB0, mw.x, mw.w)));
    }
    FragU x0fA; split4(x0A, x0fA.u);
    FragU x0fB; split4(x0B, x0fB.u);

    // ---- mlp: two independent 2-MFMA chains (A,B interleave on the pipe) ----
    f32x4 dxA = {0.f,0.f,0.f,0.f}, dxB = {0.f,0.f,0.f,0.f};
    dxA = __builtin_amdgcn_mfma_f32_16x16x32_bf16(mlpA[0].f, x0fA.f, dxA, 0,0,0);
    dxB = __builtin_amdgcn_mfma_f32_16x16x32_bf16(mlpA[0].f, x0fB.f, dxB, 0,0,0);
    dxA = __builtin_amdgcn_mfma_f32_16x16x32_bf16(mlpA[1].f, x0fA.f, dxA, 0,0,0);
    dxB = __builtin_amdgcn_mfma_f32_16x16x32_bf16(mlpA[1].f, x0fB.f, dxB, 0,0,0);
    float xvA[4], xvB[4];
    #pragma unroll
    for (int r = 0; r < 4; r++){
        xvA[r] = elu_f(dxA[r] + mlpbr[r]);
        xvB[r] = elu_f(dxB[r] + mlpbr[r]);
    }
    FragU xAA; split4(xvA, xAA.u);
    FragU xAB; split4(xvB, xAB.u);

    float o0A = 0.f, o1A = 0.f, o0B = 0.f, o1B = 0.f;

    // ---- tiles 0..3: lift2 -> ELU -> hi-dup B-frag -> agg; shared wf/ew ----
    #pragma unroll
    for (int b = 0; b < 4; b++){
        FragU wf0, wf1;
        *(u32x4*)wf0.u = *(const u32x4*)&sW2[((b*2 + 0)*64 + lane)*4];
        *(u32x4*)wf1.u = *(const u32x4*)&sW2[((b*2 + 1)*64 + lane)*4];
        f32x4 dlA = {0.f,0.f,0.f,0.f}, dlB = {0.f,0.f,0.f,0.f};
        dlA = __builtin_amdgcn_mfma_f32_16x16x32_bf16(hfA[0].f, wf0.f, dlA, 0,0,0);
        dlB = __builtin_amdgcn_mfma_f32_16x16x32_bf16(hfB[0].f, wf0.f, dlB, 0,0,0);
        dlA = __builtin_amdgcn_mfma_f32_16x16x32_bf16(hfA[1].f, wf1.f, dlA, 0,0,0);
        dlB = __builtin_amdgcn_mfma_f32_16x16x32_bf16(hfB[1].f, wf1.f, dlB, 0,0,0);
        float flA[4], flB[4];
        #pragma unroll
        for (int r = 0; r < 4; r++){
            flA[r] = elu_f(dlA[r] + b2r[b]);
            flB[r] = elu_f(dlB[r] + b2r[b]);
        }
        FragU bfgA, bfgB;
        {
            unsigned h01 = pk_bf16(flA[0], flA[1]), h23 = pk_bf16(flA[2], flA[3]);
            bfgA.u[0] = h01; bfgA.u[1] = h23; bfgA.u[2] = h01; bfgA.u[3] = h23;
        }
        {
            unsigned h01 = pk_bf16(flB[0], flB[1]), h23 = pk_bf16(flB[2], flB[3]);
            bfgB.u[0] = h01; bfgB.u[1] = h23; bfgB.u[2] = h01; bfgB.u[3] = h23;
        }
        f32x4 daA = {0.f,0.f,0.f,0.f}, daB = {0.f,0.f,0.f,0.f};
        daA = __builtin_amdgcn_mfma_f32_16x16x32_bf16(xAA.f, bfgA.f, daA, 0,0,0);
        daB = __builtin_amdgcn_mfma_f32_16x16x32_bf16(xAB.f, bfgB.f, daB, 0,0,0);
        const float4 ew = *(const float4*)&sEndw[(b*16 + lo16)*20 + quad*4];
        float ptA = daA[0]*ew.x + daA[1]*ew.y + daA[2]*ew.z + daA[3]*ew.w;
        float ptB = daB[0]*ew.x + daB[1]*ew.y + daB[2]*ew.z + daB[3]*ew.w;
        ptA += __shfl_xor(ptA, 16, 64);
        ptB += __shfl_xor(ptB, 16, 64);
        ptA += __shfl_xor(ptA, 32, 64);
        ptB += __shfl_xor(ptB, 32, 64);
        if (b == quad){ o0A = ptA; o0B = ptB; }    // c = b*16+lo16 == lane
    }
    // ---- tiles 4..7: raw F (pre-packed) -> hi-dup B-frag -> agg; shared ew ----
    #pragma unroll
    for (int bt = 0; bt < 4; bt++){
        FragU bfgA, bfgB;
        bfgA.u[0] = fA01[bt]; bfgA.u[1] = fA23[bt];
        bfgA.u[2] = fA01[bt]; bfgA.u[3] = fA23[bt];
        bfgB.u[0] = fB01[bt]; bfgB.u[1] = fB23[bt];
        bfgB.u[2] = fB01[bt]; bfgB.u[3] = fB23[bt];
        f32x4 daA = {0.f,0.f,0.f,0.f}, daB = {0.f,0.f,0.f,0.f};
        daA = __builtin_amdgcn_mfma_f32_16x16x32_bf16(xAA.f, bfgA.f, daA, 0,0,0);
        daB = __builtin_amdgcn_mfma_f32_16x16x32_bf16(xAB.f, bfgB.f, daB, 0,0,0);
        const float4 ew = *(const float4*)&sEndw[(64 + bt*16 + lo16)*20 + quad*4];
        float ptA = daA[0]*ew.x + daA[1]*ew.y + daA[2]*ew.z + daA[3]*ew.w;
        float ptB = daB[0]*ew.x + daB[1]*ew.y + daB[2]*ew.z + daB[3]*ew.w;
        ptA += __shfl_xor(ptA, 16, 64);
        ptB += __shfl_xor(ptB, 16, 64);
        ptA += __shfl_xor(ptA, 32, 64);
        ptB += __shfl_xor(ptB, 32, 64);
        if (bt == quad){ o1A = ptA; o1B = ptB; }   // c = 64 + bt*16+lo16 == 64+lane
    }

    out[(size_t)nrA*CM + lane]      = o0A + endb0;
    out[(size_t)nrA*CM + 64 + lane] = o1A + endb1;
    out[(size_t)nrB*CM + lane]      = o0B + endb0;
    out[(size_t)nrB*CM + 64 + lane] = o1B + endb1;
}

extern "C" void kernel_launch(void* const* d_in, const int* in_sizes, int n_in,
                              void* d_out, int out_size, void* d_ws, size_t ws_size,
                              hipStream_t stream)
{
    const float* p     = (const float*)d_in[0];
    const float* P     = (const float*)d_in[1];
    const float* F     = (const float*)d_in[2];
    const float* gamma = (const float*)d_in[3];
    const float* beta  = (const float*)d_in[4];
    const float* w1    = (const float*)d_in[5];
    const float* b1    = (const float*)d_in[6];
    const float* w2    = (const float*)d_in[7];
    const float* b2    = (const float*)d_in[8];
    const float* midw  = (const float*)d_in[9];
    const float* midb  = (const float*)d_in[10];
    const float* mlpw  = (const float*)d_in[11];
    const float* mlpb  = (const float*)d_in[12];
    const float* endw  = (const float*)d_in[13];
    const float* endb  = (const float*)d_in[14];
    float* ws  = (float*)d_ws;
    float* out = (float*)d_out;

    xconv_stats<<<256, 256, 0, stream>>>(p, P, w1, b1, w2, ws);
    xconv_bn   <<<1,    64, 0, stream>>>(ws, gamma, beta);
    xconv_main <<<2048, 256, 0, stream>>>(p, P, F, mlpw, mlpb, midw, midb,
                                          b2, endw, endb, out);
}